// Round 2
// baseline (972.756 us; speedup 1.0000x reference)
//
#include <hip/hip_runtime.h>
#include <hip/hip_bf16.h>
#include <cstddef>
#include <cstdint>

#define TPB 256
#define HID 128
#define GATD 512
#define HEADS 4

__device__ __forceinline__ float lrelu02(float x) { return x > 0.0f ? x : 0.2f * x; }

// ---------------- utility ----------------
__global__ void k_zero(int* __restrict__ p, int n) {
  int i = blockIdx.x * blockDim.x + threadIdx.x;
  if (i < n) p[i] = 0;
}

// ---------------- CSR build ----------------
__global__ void k_hist(const int* __restrict__ dst, int* __restrict__ cnt, int E) {
  int i = blockIdx.x * blockDim.x + threadIdx.x;
  if (i < E) atomicAdd(&cnt[dst[i]], 1);
}

__global__ void k_dinv(const int* __restrict__ cnt, float* __restrict__ dinv, int n) {
  int i = blockIdx.x * blockDim.x + threadIdx.x;
  if (i < n) dinv[i] = rsqrtf((float)(cnt[i] + 1));  // +1 = self loop
}

__global__ __launch_bounds__(1024) void k_scan(const int* __restrict__ cnt,
                                               int* __restrict__ rowp, int n) {
  __shared__ int sm[1024];
  __shared__ int carry;
  const int tid = threadIdx.x;
  if (tid == 0) carry = 0;
  __syncthreads();
  for (int base = 0; base < n; base += 1024) {
    int idx = base + tid;
    int v = (idx < n) ? cnt[idx] : 0;
    sm[tid] = v;
    __syncthreads();
    for (int off = 1; off < 1024; off <<= 1) {
      int t = (tid >= off) ? sm[tid - off] : 0;
      __syncthreads();
      sm[tid] += t;
      __syncthreads();
    }
    int incl = sm[tid];
    int c = carry;
    if (idx < n) rowp[idx] = c + incl - v;  // exclusive
    __syncthreads();
    if (tid == 1023) carry = c + sm[1023];
    __syncthreads();
  }
  if (tid == 0) rowp[n] = carry;
}

__global__ void k_fill(const int* __restrict__ src, const int* __restrict__ dst,
                       const int* __restrict__ rowp, int* __restrict__ cur,
                       int* __restrict__ colsrc, int E) {
  int i = blockIdx.x * blockDim.x + threadIdx.x;
  if (i < E) {
    int d = dst[i];
    int pos = rowp[d] + atomicAdd(&cur[d], 1);
    colsrc[pos] = src[i];
  }
}

// ---------------- fp32 tiled GEMM: C = act(A[M,K] @ W[K,NC] + bias) ----------------
template <int BN, int TN, bool RELU, bool BIAS>
__global__ __launch_bounds__(256) void k_gemm(const float* __restrict__ A,
                                              const float* __restrict__ W,
                                              const float* __restrict__ bias,
                                              float* __restrict__ C, int M, int K, int NC) {
  constexpr int BM = 128, BK = 32, TM = 8;
  __shared__ float As[BK][BM + 4];  // transposed A tile: As[k][m]
  __shared__ float Ws[BK][BN];
  const int tid = threadIdx.x;
  const int m0 = blockIdx.x * BM;
  const int n0 = blockIdx.y * BN;
  const int tx = tid & 15, ty = tid >> 4;
  float acc[TM][TN];
#pragma unroll
  for (int r = 0; r < TM; ++r)
#pragma unroll
    for (int c = 0; c < TN; ++c) acc[r][c] = 0.0f;

  for (int k0 = 0; k0 < K; k0 += BK) {
#pragma unroll
    for (int t = tid; t < BM * BK / 4; t += 256) {
      int kq = t & (BK / 4 - 1);
      int r = t / (BK / 4);
      int grow = m0 + r;
      float4 v = make_float4(0.f, 0.f, 0.f, 0.f);
      if (grow < M) v = *(const float4*)(A + (size_t)grow * K + k0 + kq * 4);
      As[kq * 4 + 0][r] = v.x;
      As[kq * 4 + 1][r] = v.y;
      As[kq * 4 + 2][r] = v.z;
      As[kq * 4 + 3][r] = v.w;
    }
#pragma unroll
    for (int t = tid; t < BK * BN / 4; t += 256) {
      int nq = t % (BN / 4);
      int kr = t / (BN / 4);
      *(float4*)&Ws[kr][nq * 4] = *(const float4*)(W + (size_t)(k0 + kr) * NC + n0 + nq * 4);
    }
    __syncthreads();
#pragma unroll 4
    for (int kk = 0; kk < BK; ++kk) {
      float a[TM], b[TN];
      float4 a0 = *(const float4*)&As[kk][ty * TM];
      float4 a1 = *(const float4*)&As[kk][ty * TM + 4];
      a[0] = a0.x; a[1] = a0.y; a[2] = a0.z; a[3] = a0.w;
      a[4] = a1.x; a[5] = a1.y; a[6] = a1.z; a[7] = a1.w;
#pragma unroll
      for (int c = 0; c < TN; c += 4) {
        float4 bv = *(const float4*)&Ws[kk][tx * TN + c];
        b[c] = bv.x; b[c + 1] = bv.y; b[c + 2] = bv.z; b[c + 3] = bv.w;
      }
#pragma unroll
      for (int r = 0; r < TM; ++r)
#pragma unroll
        for (int c = 0; c < TN; ++c) acc[r][c] = fmaf(a[r], b[c], acc[r][c]);
    }
    __syncthreads();
  }
#pragma unroll
  for (int r = 0; r < TM; ++r) {
    int grow = m0 + ty * TM + r;
    if (grow < M) {
      float* Crow = C + (size_t)grow * NC + n0 + tx * TN;
#pragma unroll
      for (int c = 0; c < TN; c += 4) {
        float4 v = make_float4(acc[r][c], acc[r][c + 1], acc[r][c + 2], acc[r][c + 3]);
        if (BIAS) {
          const float* bp = bias + n0 + tx * TN + c;
          v.x += bp[0]; v.y += bp[1]; v.z += bp[2]; v.w += bp[3];
        }
        if (RELU) {
          v.x = fmaxf(v.x, 0.f); v.y = fmaxf(v.y, 0.f);
          v.z = fmaxf(v.z, 0.f); v.w = fmaxf(v.w, 0.f);
        }
        *(float4*)(Crow + c) = v;
      }
    }
  }
}

// ---------------- GCN aggregate + bias + LayerNorm + ReLU (+residual), wave/node ----------------
template <bool RES>
__global__ __launch_bounds__(256) void k_gcn_agg(const float* __restrict__ xw,
                                                 const float* __restrict__ dinv,
                                                 const int* __restrict__ rowp,
                                                 const int* __restrict__ colsrc,
                                                 const float* __restrict__ bias,
                                                 const float* __restrict__ gamma,
                                                 const float* __restrict__ beta,
                                                 const float* __restrict__ resid,
                                                 float* __restrict__ out, int n) {
  const int lane = threadIdx.x & 63;
  const int i = blockIdx.x * 4 + (threadIdx.x >> 6);
  if (i >= n) return;
  const float di = dinv[i];
  const int c = lane * 2;
  float2 v = *(const float2*)(xw + (size_t)i * HID + c);
  float a0 = v.x * di * di, a1 = v.y * di * di;  // self loop
  const int e0 = rowp[i], e1 = rowp[i + 1];
  for (int j = e0; j < e1; ++j) {
    int s = colsrc[j];
    float w = dinv[s] * di;
    float2 u = *(const float2*)(xw + (size_t)s * HID + c);
    a0 = fmaf(u.x, w, a0);
    a1 = fmaf(u.y, w, a1);
  }
  a0 += bias[c];
  a1 += bias[c + 1];
  float s1 = a0 + a1, s2 = a0 * a0 + a1 * a1;
#pragma unroll
  for (int m = 32; m >= 1; m >>= 1) {
    s1 += __shfl_xor(s1, m);
    s2 += __shfl_xor(s2, m);
  }
  float mu = s1 * (1.0f / HID);
  float var = s2 * (1.0f / HID) - mu * mu;
  float rstd = rsqrtf(var + 1e-5f);
  float y0 = fmaxf((a0 - mu) * rstd * gamma[c] + beta[c], 0.0f);
  float y1 = fmaxf((a1 - mu) * rstd * gamma[c + 1] + beta[c + 1], 0.0f);
  if (RES) {
    float2 r = *(const float2*)(resid + (size_t)i * HID + c);
    y0 += r.x;
    y1 += r.y;
  }
  *(float2*)(out + (size_t)i * HID + c) = make_float2(y0, y1);
}

// ---------------- GAT per-node attention scores a_s,a_d (wave/node) ----------------
__global__ __launch_bounds__(256) void k_gat_scores(const float* __restrict__ xwg,
                                                    const float* __restrict__ att_src,
                                                    const float* __restrict__ att_dst,
                                                    float* __restrict__ a_s,
                                                    float* __restrict__ a_d, int n) {
  const int lane = threadIdx.x & 63;
  const int i = blockIdx.x * 4 + (threadIdx.x >> 6);
  if (i >= n) return;
  const int col = lane * 8;
  const int h = lane >> 4;
  const int cl = col & (HID - 1);
  const float4* xp = (const float4*)(xwg + (size_t)i * GATD + col);
  float4 x0 = xp[0], x1 = xp[1];
  const float4* sp = (const float4*)(att_src + h * HID + cl);
  float4 s0 = sp[0], s1 = sp[1];
  const float4* dp = (const float4*)(att_dst + h * HID + cl);
  float4 d0 = dp[0], d1 = dp[1];
  float ps = x0.x * s0.x + x0.y * s0.y + x0.z * s0.z + x0.w * s0.w +
             x1.x * s1.x + x1.y * s1.y + x1.z * s1.z + x1.w * s1.w;
  float pd = x0.x * d0.x + x0.y * d0.y + x0.z * d0.z + x0.w * d0.w +
             x1.x * d1.x + x1.y * d1.y + x1.z * d1.z + x1.w * d1.w;
#pragma unroll
  for (int m = 1; m < 16; m <<= 1) {
    ps += __shfl_xor(ps, m);
    pd += __shfl_xor(pd, m);
  }
  if ((lane & 15) == 0) {
    a_s[i * HEADS + h] = ps;
    a_d[i * HEADS + h] = pd;
  }
}

// ---------------- GAT softmax-aggregate (wave/node) ----------------
__global__ __launch_bounds__(256) void k_gat_agg(const float* __restrict__ xwg,
                                                 const float* __restrict__ a_s,
                                                 const float* __restrict__ a_d,
                                                 const int* __restrict__ rowp,
                                                 const int* __restrict__ colsrc,
                                                 const float* __restrict__ bias,
                                                 float* __restrict__ out, int n) {
  const int lane = threadIdx.x & 63;
  const int i = blockIdx.x * 4 + (threadIdx.x >> 6);
  if (i >= n) return;
  const float4 adv = *(const float4*)(a_d + i * 4);
  const float4 asv = *(const float4*)(a_s + i * 4);
  float es0 = lrelu02(asv.x + adv.x);
  float es1 = lrelu02(asv.y + adv.y);
  float es2 = lrelu02(asv.z + adv.z);
  float es3 = lrelu02(asv.w + adv.w);
  const int e0 = rowp[i], e1 = rowp[i + 1];
  // pass 1: max (lanes split edges; init includes self loop)
  float m0 = es0, m1 = es1, m2 = es2, m3 = es3;
  for (int j = e0 + lane; j < e1; j += 64) {
    int s = colsrc[j];
    const float4 av = *(const float4*)(a_s + s * 4);
    m0 = fmaxf(m0, lrelu02(av.x + adv.x));
    m1 = fmaxf(m1, lrelu02(av.y + adv.y));
    m2 = fmaxf(m2, lrelu02(av.z + adv.z));
    m3 = fmaxf(m3, lrelu02(av.w + adv.w));
  }
#pragma unroll
  for (int m = 32; m >= 1; m >>= 1) {
    m0 = fmaxf(m0, __shfl_xor(m0, m));
    m1 = fmaxf(m1, __shfl_xor(m1, m));
    m2 = fmaxf(m2, __shfl_xor(m2, m));
    m3 = fmaxf(m3, __shfl_xor(m3, m));
  }
  // pass 2: denom
  float d0 = 0.f, d1 = 0.f, d2 = 0.f, d3 = 0.f;
  for (int j = e0 + lane; j < e1; j += 64) {
    int s = colsrc[j];
    const float4 av = *(const float4*)(a_s + s * 4);
    d0 += __expf(lrelu02(av.x + adv.x) - m0);
    d1 += __expf(lrelu02(av.y + adv.y) - m1);
    d2 += __expf(lrelu02(av.z + adv.z) - m2);
    d3 += __expf(lrelu02(av.w + adv.w) - m3);
  }
#pragma unroll
  for (int m = 32; m >= 1; m >>= 1) {
    d0 += __shfl_xor(d0, m);
    d1 += __shfl_xor(d1, m);
    d2 += __shfl_xor(d2, m);
    d3 += __shfl_xor(d3, m);
  }
  d0 += __expf(es0 - m0);
  d1 += __expf(es1 - m1);
  d2 += __expf(es2 - m2);
  d3 += __expf(es3 - m3);
  const float inv0 = 1.0f / d0, inv1 = 1.0f / d1, inv2 = 1.0f / d2, inv3 = 1.0f / d3;
  const int col = lane * 8;
  const int h = lane >> 4;
  const float mh = (h < 2) ? (h == 0 ? m0 : m1) : (h == 2 ? m2 : m3);
  const float invh = (h < 2) ? (h == 0 ? inv0 : inv1) : (h == 2 ? inv2 : inv3);
  const float adh = (h < 2) ? (h == 0 ? adv.x : adv.y) : (h == 2 ? adv.z : adv.w);
  const float esh = (h < 2) ? (h == 0 ? es0 : es1) : (h == 2 ? es2 : es3);
  // pass 3: alpha-weighted message accumulation (init = self loop)
  const float aself = __expf(esh - mh) * invh;
  const float4* xp = (const float4*)(xwg + (size_t)i * GATD + col);
  float4 acc0 = xp[0], acc1 = xp[1];
  acc0.x *= aself; acc0.y *= aself; acc0.z *= aself; acc0.w *= aself;
  acc1.x *= aself; acc1.y *= aself; acc1.z *= aself; acc1.w *= aself;
  for (int j = e0; j < e1; ++j) {
    int s = colsrc[j];
    float al = __expf(lrelu02(a_s[s * 4 + h] + adh) - mh) * invh;
    const float4* up = (const float4*)(xwg + (size_t)s * GATD + col);
    float4 u0 = up[0], u1 = up[1];
    acc0.x = fmaf(u0.x, al, acc0.x); acc0.y = fmaf(u0.y, al, acc0.y);
    acc0.z = fmaf(u0.z, al, acc0.z); acc0.w = fmaf(u0.w, al, acc0.w);
    acc1.x = fmaf(u1.x, al, acc1.x); acc1.y = fmaf(u1.y, al, acc1.y);
    acc1.z = fmaf(u1.z, al, acc1.z); acc1.w = fmaf(u1.w, al, acc1.w);
  }
  const float4* bp = (const float4*)(bias + col);
  float4 b0 = bp[0], b1 = bp[1];
  acc0.x += b0.x; acc0.y += b0.y; acc0.z += b0.z; acc0.w += b0.w;
  acc1.x += b1.x; acc1.y += b1.y; acc1.z += b1.z; acc1.w += b1.w;
  float4* op = (float4*)(out + (size_t)i * GATD + col);
  op[0] = acc0;
  op[1] = acc1;
}

extern "C" void kernel_launch(void* const* d_in, const int* in_sizes, int n_in,
                              void* d_out, int out_size, void* d_ws, size_t ws_size,
                              hipStream_t stream) {
  const float* x = (const float*)d_in[0];
  const int* ei = (const int*)d_in[1];
  const float* Win = (const float*)d_in[2];
  const float* bin = (const float*)d_in[3];
  const float* Wg1 = (const float*)d_in[4];
  const float* bg1 = (const float*)d_in[5];
  const float* g1g = (const float*)d_in[6];
  const float* g1b = (const float*)d_in[7];
  const float* Wg2 = (const float*)d_in[8];
  const float* bg2 = (const float*)d_in[9];
  const float* g2g = (const float*)d_in[10];
  const float* g2b = (const float*)d_in[11];
  const float* Wgat = (const float*)d_in[12];
  const float* att_s = (const float*)d_in[13];
  const float* att_d = (const float*)d_in[14];
  const float* bgat = (const float*)d_in[15];
  const float* Wao = (const float*)d_in[16];
  const float* bao = (const float*)d_in[17];
  const float* Wout = (const float*)d_in[18];
  const float* bout = (const float*)d_in[19];

  const int N = in_sizes[0] / 256;
  const int E = in_sizes[1] / 2;
  const int* src = ei;
  const int* dst = ei + E;

  // ---- workspace layout (float elements), total ~210.4 MB ----
  // [0, 4*N*HID)          : reuse region R = h0|xw|x1|x2 ; later reused as gat[N,512]
  // [4*N*HID, 8*N*HID)    : xwg[N,512]                   ; later reused as att[N,128]
  // then dinv[N], a_s[4N], a_d[4N], ints: cnt[N],cur[N],rowp[N+1],colsrc[E]
  float* F = (float*)d_ws;
  size_t o = 0;
  float* h0 = F + o;  o += (size_t)N * HID;
  float* xw = F + o;  o += (size_t)N * HID;
  float* x1 = F + o;  o += (size_t)N * HID;
  float* x2 = F + o;  o += (size_t)N * HID;
  float* gat = h0;                       // reuses h0|xw|x1|x2 (all dead by GAT agg)
  float* xwg = F + o; o += (size_t)N * GATD;
  float* att = xwg;                      // reuses xwg (dead after GAT agg)
  float* dinv = F + o; o += (size_t)N;
  float* a_s = F + o; o += (size_t)N * HEADS;
  float* a_d = F + o; o += (size_t)N * HEADS;
  int* I = (int*)(F + o);
  int* cnt = I;
  int* cur = I + N;
  int* rowp = I + 2 * N;
  int* colsrc = I + 3 * N + 1;

  const int eb = (E + TPB - 1) / TPB;
  const int nb = (N + TPB - 1) / TPB;
  const int zb = (2 * N + TPB - 1) / TPB;
  const int ab = (N + 3) / 4;
  const int gm = (N + 127) / 128;

  k_zero<<<zb, TPB, 0, stream>>>(cnt, 2 * N);  // cnt + cur
  k_hist<<<eb, TPB, 0, stream>>>(dst, cnt, E);
  k_dinv<<<nb, TPB, 0, stream>>>(cnt, dinv, N);
  k_scan<<<1, 1024, 0, stream>>>(cnt, rowp, N);
  k_fill<<<eb, TPB, 0, stream>>>(src, dst, rowp, cur, colsrc, E);

  // h0 = relu(x @ Win + bin)            [N,256]x[256,128]
  k_gemm<128, 8, true, true><<<dim3(gm, 1), 256, 0, stream>>>(x, Win, bin, h0, N, 256, 128);
  // GCN layer 1
  k_gemm<128, 8, false, false><<<dim3(gm, 1), 256, 0, stream>>>(h0, Wg1, nullptr, xw, N, 128, 128);
  k_gcn_agg<false><<<ab, 256, 0, stream>>>(xw, dinv, rowp, colsrc, bg1, g1g, g1b, nullptr, x1, N);
  // GCN layer 2 (+residual)
  k_gemm<128, 8, false, false><<<dim3(gm, 1), 256, 0, stream>>>(x1, Wg2, nullptr, xw, N, 128, 128);
  k_gcn_agg<true><<<ab, 256, 0, stream>>>(xw, dinv, rowp, colsrc, bg2, g2g, g2b, x1, x2, N);
  // GAT: xwg = x2 @ Wgat                [N,128]x[128,512]
  k_gemm<128, 8, false, false><<<dim3(gm, 4), 256, 0, stream>>>(x2, Wgat, nullptr, xwg, N, 128, 512);
  k_gat_scores<<<ab, 256, 0, stream>>>(xwg, att_s, att_d, a_s, a_d, N);
  // gat overwrites h0|xw|x1|x2 (dead); reads xwg
  k_gat_agg<<<ab, 256, 0, stream>>>(xwg, a_s, a_d, rowp, colsrc, bgat, gat, N);
  // att = relu(gat @ Wao + bao)         [N,512]x[512,128]  (att overwrites xwg region)
  k_gemm<128, 8, true, true><<<dim3(gm, 1), 256, 0, stream>>>(gat, Wao, bao, att, N, 512, 128);
  // out = att @ Wout + bout             [N,128]x[128,64]
  k_gemm<64, 4, false, true><<<dim3(gm, 1), 256, 0, stream>>>(att, Wout, bout, (float*)d_out, N, 128, 64);
}

// Round 3
// 801.284 us; speedup vs baseline: 1.2140x; 1.2140x over previous
//
#include <hip/hip_runtime.h>
#include <hip/hip_bf16.h>
#include <cstddef>
#include <cstdint>

#define TPB 256
#define HID 128
#define GATD 512
#define HEADS 4

typedef __attribute__((ext_vector_type(8))) short bf16x8;
typedef __attribute__((ext_vector_type(4))) float f32x4;

__device__ __forceinline__ float lrelu02(float x) { return x > 0.0f ? x : 0.2f * x; }

__device__ __forceinline__ unsigned short f2bf_rn(float f) {
  uint32_t u = __float_as_uint(f);
  u += 0x7fff + ((u >> 16) & 1);
  return (unsigned short)(u >> 16);
}
__device__ __forceinline__ float bf2f(unsigned short h) {
  return __uint_as_float(((uint32_t)h) << 16);
}
__device__ __forceinline__ void split_bf(float a, unsigned short& hi, unsigned short& lo) {
  hi = f2bf_rn(a);
  lo = f2bf_rn(a - bf2f(hi));
}

// ---------------- utility ----------------
__global__ void k_zero(int* __restrict__ p, int n) {
  int i = blockIdx.x * blockDim.x + threadIdx.x;
  if (i < n) p[i] = 0;
}

// ---------------- CSR build ----------------
__global__ void k_hist(const int* __restrict__ dst, int* __restrict__ cnt, int E) {
  int i = blockIdx.x * blockDim.x + threadIdx.x;
  if (i < E) atomicAdd(&cnt[dst[i]], 1);
}

__global__ void k_dinv(const int* __restrict__ cnt, float* __restrict__ dinv, int n) {
  int i = blockIdx.x * blockDim.x + threadIdx.x;
  if (i < n) dinv[i] = rsqrtf((float)(cnt[i] + 1));  // +1 = self loop
}

__global__ __launch_bounds__(1024) void k_scan(const int* __restrict__ cnt,
                                               int* __restrict__ rowp, int n) {
  __shared__ int sm[1024];
  __shared__ int carry;
  const int tid = threadIdx.x;
  if (tid == 0) carry = 0;
  __syncthreads();
  for (int base = 0; base < n; base += 1024) {
    int idx = base + tid;
    int v = (idx < n) ? cnt[idx] : 0;
    sm[tid] = v;
    __syncthreads();
    for (int off = 1; off < 1024; off <<= 1) {
      int t = (tid >= off) ? sm[tid - off] : 0;
      __syncthreads();
      sm[tid] += t;
      __syncthreads();
    }
    int incl = sm[tid];
    int c = carry;
    if (idx < n) rowp[idx] = c + incl - v;  // exclusive
    __syncthreads();
    if (tid == 1023) carry = c + sm[1023];
    __syncthreads();
  }
  if (tid == 0) rowp[n] = carry;
}

__global__ void k_fill(const int* __restrict__ src, const int* __restrict__ dst,
                       const int* __restrict__ rowp, int* __restrict__ cur,
                       int* __restrict__ colsrc, int E) {
  int i = blockIdx.x * blockDim.x + threadIdx.x;
  if (i < E) {
    int d = dst[i];
    int pos = rowp[d] + atomicAdd(&cur[d], 1);
    colsrc[pos] = src[i];
  }
}

// ---------------- MFMA GEMM with split-bf16 (hi/lo) emulated fp32 ----------------
// C = act(A[M,K] @ W[K,NC] + bias).  BM=128, BK=32, 4 waves 2x2.
// A*B ~= Ah*Bh + Ah*Bl + Al*Bh  (error ~2^-17 rel).
// LDS layout: [kg][row][8] bf16 so an MFMA frag = one ds_read_b128
// (mfma_f32_16x16x32_bf16: A lane l holds row=l&15, k=(l>>4)*8+j;
//  B lane l holds col=l&15, k=(l>>4)*8+j; D: col=lane&15, row=(lane>>4)*4+r [m89]).
template <int BN, int WCF, bool RELU, bool BIAS>
__global__ __launch_bounds__(256) void k_gemm_mfma(const float* __restrict__ A,
                                                   const float* __restrict__ W,
                                                   const float* __restrict__ bias,
                                                   float* __restrict__ C,
                                                   int M, int K, int NC) {
  constexpr int BM = 128;
  constexpr int LOG2BN = (BN == 128) ? 7 : 6;
  __shared__ alignas(16) unsigned short Ah[4][BM][8], Al[4][BM][8];
  __shared__ alignas(16) unsigned short Bh[4][BN][8], Bl[4][BN][8];

  const int tid = threadIdx.x;
  const int lane = tid & 63;
  const int wid = tid >> 6;
  const int wr = wid >> 1, wc = wid & 1;
  const int m0 = blockIdx.x * BM;
  const int n0 = blockIdx.y * BN;

  f32x4 acc[4][WCF];
#pragma unroll
  for (int mr = 0; mr < 4; ++mr)
#pragma unroll
    for (int nc = 0; nc < WCF; ++nc) acc[mr][nc] = (f32x4){0.f, 0.f, 0.f, 0.f};

  const int arow = tid >> 1;      // 0..127
  const int ahalf = tid & 1;      // which 16-k half
  const bool aok = (m0 + arow) < M;
  const float* Ap = A + (size_t)(m0 + arow) * K + ahalf * 16;
  const int fr = lane & 15;       // frag row/col
  const int g = lane >> 4;        // k-group

  for (int k0 = 0; k0 < K; k0 += 32) {
    // ---- stage A (fp32 -> hi/lo bf16) ----
    float av[16];
    if (aok) {
      const float4* p = (const float4*)(Ap + k0);
      float4 q0 = p[0], q1 = p[1], q2 = p[2], q3 = p[3];
      av[0] = q0.x; av[1] = q0.y; av[2] = q0.z; av[3] = q0.w;
      av[4] = q1.x; av[5] = q1.y; av[6] = q1.z; av[7] = q1.w;
      av[8] = q2.x; av[9] = q2.y; av[10] = q2.z; av[11] = q2.w;
      av[12] = q3.x; av[13] = q3.y; av[14] = q3.z; av[15] = q3.w;
    } else {
#pragma unroll
      for (int j = 0; j < 16; ++j) av[j] = 0.f;
    }
#pragma unroll
    for (int gg = 0; gg < 2; ++gg) {
      uint32_t hw[4], lw[4];
#pragma unroll
      for (int q = 0; q < 4; ++q) {
        unsigned short h0, l0, h1, l1;
        split_bf(av[gg * 8 + 2 * q], h0, l0);
        split_bf(av[gg * 8 + 2 * q + 1], h1, l1);
        hw[q] = (uint32_t)h0 | ((uint32_t)h1 << 16);
        lw[q] = (uint32_t)l0 | ((uint32_t)l1 << 16);
      }
      const int kg = ahalf * 2 + gg;
      *(uint4*)&Ah[kg][arow][0] = make_uint4(hw[0], hw[1], hw[2], hw[3]);
      *(uint4*)&Al[kg][arow][0] = make_uint4(lw[0], lw[1], lw[2], lw[3]);
    }
    // ---- stage B (transpose-free: each thread grabs 8 consecutive k of one column) ----
#pragma unroll
    for (int b = 0; b < (BN * 4) / 256; ++b) {
      const int it = tid + b * 256;
      const int n = it & (BN - 1);
      const int kg = it >> LOG2BN;
      const float* Wp = W + (size_t)(k0 + kg * 8) * NC + n0 + n;
      uint32_t hw[4], lw[4];
#pragma unroll
      for (int q = 0; q < 4; ++q) {
        float v0 = Wp[(size_t)(2 * q) * NC];
        float v1 = Wp[(size_t)(2 * q + 1) * NC];
        unsigned short h0, l0, h1, l1;
        split_bf(v0, h0, l0);
        split_bf(v1, h1, l1);
        hw[q] = (uint32_t)h0 | ((uint32_t)h1 << 16);
        lw[q] = (uint32_t)l0 | ((uint32_t)l1 << 16);
      }
      *(uint4*)&Bh[kg][n][0] = make_uint4(hw[0], hw[1], hw[2], hw[3]);
      *(uint4*)&Bl[kg][n][0] = make_uint4(lw[0], lw[1], lw[2], lw[3]);
    }
    __syncthreads();
    // ---- frags + MFMA ----
    bf16x8 ahf[4], alf[4], bhf[WCF], blf[WCF];
#pragma unroll
    for (int mr = 0; mr < 4; ++mr) {
      const int row = wr * 64 + mr * 16 + fr;
      ahf[mr] = *(const bf16x8*)&Ah[g][row][0];
      alf[mr] = *(const bf16x8*)&Al[g][row][0];
    }
#pragma unroll
    for (int nc = 0; nc < WCF; ++nc) {
      const int col = wc * WCF * 16 + nc * 16 + fr;
      bhf[nc] = *(const bf16x8*)&Bh[g][col][0];
      blf[nc] = *(const bf16x8*)&Bl[g][col][0];
    }
#pragma unroll
    for (int mr = 0; mr < 4; ++mr)
#pragma unroll
      for (int nc = 0; nc < WCF; ++nc) {
        acc[mr][nc] = __builtin_amdgcn_mfma_f32_16x16x32_bf16(ahf[mr], bhf[nc], acc[mr][nc], 0, 0, 0);
        acc[mr][nc] = __builtin_amdgcn_mfma_f32_16x16x32_bf16(ahf[mr], blf[nc], acc[mr][nc], 0, 0, 0);
        acc[mr][nc] = __builtin_amdgcn_mfma_f32_16x16x32_bf16(alf[mr], bhf[nc], acc[mr][nc], 0, 0, 0);
      }
    __syncthreads();
  }
  // ---- epilogue ----
#pragma unroll
  for (int mr = 0; mr < 4; ++mr) {
#pragma unroll
    for (int nc = 0; nc < WCF; ++nc) {
      const int col = n0 + wc * WCF * 16 + nc * 16 + fr;
      const float bv = BIAS ? bias[col] : 0.f;
#pragma unroll
      for (int r = 0; r < 4; ++r) {
        const int grow = m0 + wr * 64 + mr * 16 + g * 4 + r;
        if (grow < M) {
          float v = acc[mr][nc][r] + bv;
          if (RELU) v = fmaxf(v, 0.f);
          C[(size_t)grow * NC + col] = v;
        }
      }
    }
  }
}

// ---------------- GCN aggregate + bias + LayerNorm + ReLU (+residual), wave/node ----------------
template <bool RES>
__global__ __launch_bounds__(256) void k_gcn_agg(const float* __restrict__ xw,
                                                 const float* __restrict__ dinv,
                                                 const int* __restrict__ rowp,
                                                 const int* __restrict__ colsrc,
                                                 const float* __restrict__ bias,
                                                 const float* __restrict__ gamma,
                                                 const float* __restrict__ beta,
                                                 const float* __restrict__ resid,
                                                 float* __restrict__ out, int n) {
  const int lane = threadIdx.x & 63;
  const int i = blockIdx.x * 4 + (threadIdx.x >> 6);
  if (i >= n) return;
  const float di = dinv[i];
  const int c = lane * 2;
  float2 v = *(const float2*)(xw + (size_t)i * HID + c);
  float a0 = v.x * di * di, a1 = v.y * di * di;  // self loop
  const int e0 = rowp[i], e1 = rowp[i + 1];
  for (int j = e0; j < e1; ++j) {
    int s = colsrc[j];
    float w = dinv[s] * di;
    float2 u = *(const float2*)(xw + (size_t)s * HID + c);
    a0 = fmaf(u.x, w, a0);
    a1 = fmaf(u.y, w, a1);
  }
  a0 += bias[c];
  a1 += bias[c + 1];
  float s1 = a0 + a1, s2 = a0 * a0 + a1 * a1;
#pragma unroll
  for (int m = 32; m >= 1; m >>= 1) {
    s1 += __shfl_xor(s1, m);
    s2 += __shfl_xor(s2, m);
  }
  float mu = s1 * (1.0f / HID);
  float var = s2 * (1.0f / HID) - mu * mu;
  float rstd = rsqrtf(var + 1e-5f);
  float y0 = fmaxf((a0 - mu) * rstd * gamma[c] + beta[c], 0.0f);
  float y1 = fmaxf((a1 - mu) * rstd * gamma[c + 1] + beta[c + 1], 0.0f);
  if (RES) {
    float2 r = *(const float2*)(resid + (size_t)i * HID + c);
    y0 += r.x;
    y1 += r.y;
  }
  *(float2*)(out + (size_t)i * HID + c) = make_float2(y0, y1);
}

// ---------------- GAT per-node attention scores a_s,a_d (wave/node) ----------------
__global__ __launch_bounds__(256) void k_gat_scores(const float* __restrict__ xwg,
                                                    const float* __restrict__ att_src,
                                                    const float* __restrict__ att_dst,
                                                    float* __restrict__ a_s,
                                                    float* __restrict__ a_d, int n) {
  const int lane = threadIdx.x & 63;
  const int i = blockIdx.x * 4 + (threadIdx.x >> 6);
  if (i >= n) return;
  const int col = lane * 8;
  const int h = lane >> 4;
  const int cl = col & (HID - 1);
  const float4* xp = (const float4*)(xwg + (size_t)i * GATD + col);
  float4 x0 = xp[0], x1 = xp[1];
  const float4* sp = (const float4*)(att_src + h * HID + cl);
  float4 s0 = sp[0], s1 = sp[1];
  const float4* dp = (const float4*)(att_dst + h * HID + cl);
  float4 d0 = dp[0], d1 = dp[1];
  float ps = x0.x * s0.x + x0.y * s0.y + x0.z * s0.z + x0.w * s0.w +
             x1.x * s1.x + x1.y * s1.y + x1.z * s1.z + x1.w * s1.w;
  float pd = x0.x * d0.x + x0.y * d0.y + x0.z * d0.z + x0.w * d0.w +
             x1.x * d1.x + x1.y * d1.y + x1.z * d1.z + x1.w * d1.w;
#pragma unroll
  for (int m = 1; m < 16; m <<= 1) {
    ps += __shfl_xor(ps, m);
    pd += __shfl_xor(pd, m);
  }
  if ((lane & 15) == 0) {
    a_s[i * HEADS + h] = ps;
    a_d[i * HEADS + h] = pd;
  }
}

// ---------------- GAT softmax-aggregate (wave/node) ----------------
__global__ __launch_bounds__(256) void k_gat_agg(const float* __restrict__ xwg,
                                                 const float* __restrict__ a_s,
                                                 const float* __restrict__ a_d,
                                                 const int* __restrict__ rowp,
                                                 const int* __restrict__ colsrc,
                                                 const float* __restrict__ bias,
                                                 float* __restrict__ out, int n) {
  const int lane = threadIdx.x & 63;
  const int i = blockIdx.x * 4 + (threadIdx.x >> 6);
  if (i >= n) return;
  const float4 adv = *(const float4*)(a_d + i * 4);
  const float4 asv = *(const float4*)(a_s + i * 4);
  float es0 = lrelu02(asv.x + adv.x);
  float es1 = lrelu02(asv.y + adv.y);
  float es2 = lrelu02(asv.z + adv.z);
  float es3 = lrelu02(asv.w + adv.w);
  const int e0 = rowp[i], e1 = rowp[i + 1];
  float m0 = es0, m1 = es1, m2 = es2, m3 = es3;
  for (int j = e0 + lane; j < e1; j += 64) {
    int s = colsrc[j];
    const float4 av = *(const float4*)(a_s + s * 4);
    m0 = fmaxf(m0, lrelu02(av.x + adv.x));
    m1 = fmaxf(m1, lrelu02(av.y + adv.y));
    m2 = fmaxf(m2, lrelu02(av.z + adv.z));
    m3 = fmaxf(m3, lrelu02(av.w + adv.w));
  }
#pragma unroll
  for (int m = 32; m >= 1; m >>= 1) {
    m0 = fmaxf(m0, __shfl_xor(m0, m));
    m1 = fmaxf(m1, __shfl_xor(m1, m));
    m2 = fmaxf(m2, __shfl_xor(m2, m));
    m3 = fmaxf(m3, __shfl_xor(m3, m));
  }
  float d0 = 0.f, d1 = 0.f, d2 = 0.f, d3 = 0.f;
  for (int j = e0 + lane; j < e1; j += 64) {
    int s = colsrc[j];
    const float4 av = *(const float4*)(a_s + s * 4);
    d0 += __expf(lrelu02(av.x + adv.x) - m0);
    d1 += __expf(lrelu02(av.y + adv.y) - m1);
    d2 += __expf(lrelu02(av.z + adv.z) - m2);
    d3 += __expf(lrelu02(av.w + adv.w) - m3);
  }
#pragma unroll
  for (int m = 32; m >= 1; m >>= 1) {
    d0 += __shfl_xor(d0, m);
    d1 += __shfl_xor(d1, m);
    d2 += __shfl_xor(d2, m);
    d3 += __shfl_xor(d3, m);
  }
  d0 += __expf(es0 - m0);
  d1 += __expf(es1 - m1);
  d2 += __expf(es2 - m2);
  d3 += __expf(es3 - m3);
  const float inv0 = 1.0f / d0, inv1 = 1.0f / d1, inv2 = 1.0f / d2, inv3 = 1.0f / d3;
  const int col = lane * 8;
  const int h = lane >> 4;
  const float mh = (h < 2) ? (h == 0 ? m0 : m1) : (h == 2 ? m2 : m3);
  const float invh = (h < 2) ? (h == 0 ? inv0 : inv1) : (h == 2 ? inv2 : inv3);
  const float adh = (h < 2) ? (h == 0 ? adv.x : adv.y) : (h == 2 ? adv.z : adv.w);
  const float esh = (h < 2) ? (h == 0 ? es0 : es1) : (h == 2 ? es2 : es3);
  const float aself = __expf(esh - mh) * invh;
  const float4* xp = (const float4*)(xwg + (size_t)i * GATD + col);
  float4 acc0 = xp[0], acc1 = xp[1];
  acc0.x *= aself; acc0.y *= aself; acc0.z *= aself; acc0.w *= aself;
  acc1.x *= aself; acc1.y *= aself; acc1.z *= aself; acc1.w *= aself;
  for (int j = e0; j < e1; ++j) {
    int s = colsrc[j];
    float al = __expf(lrelu02(a_s[s * 4 + h] + adh) - mh) * invh;
    const float4* up = (const float4*)(xwg + (size_t)s * GATD + col);
    float4 u0 = up[0], u1 = up[1];
    acc0.x = fmaf(u0.x, al, acc0.x); acc0.y = fmaf(u0.y, al, acc0.y);
    acc0.z = fmaf(u0.z, al, acc0.z); acc0.w = fmaf(u0.w, al, acc0.w);
    acc1.x = fmaf(u1.x, al, acc1.x); acc1.y = fmaf(u1.y, al, acc1.y);
    acc1.z = fmaf(u1.z, al, acc1.z); acc1.w = fmaf(u1.w, al, acc1.w);
  }
  const float4* bp = (const float4*)(bias + col);
  float4 b0 = bp[0], b1 = bp[1];
  acc0.x += b0.x; acc0.y += b0.y; acc0.z += b0.z; acc0.w += b0.w;
  acc1.x += b1.x; acc1.y += b1.y; acc1.z += b1.z; acc1.w += b1.w;
  float4* op = (float4*)(out + (size_t)i * GATD + col);
  op[0] = acc0;
  op[1] = acc1;
}

extern "C" void kernel_launch(void* const* d_in, const int* in_sizes, int n_in,
                              void* d_out, int out_size, void* d_ws, size_t ws_size,
                              hipStream_t stream) {
  const float* x = (const float*)d_in[0];
  const int* ei = (const int*)d_in[1];
  const float* Win = (const float*)d_in[2];
  const float* bin = (const float*)d_in[3];
  const float* Wg1 = (const float*)d_in[4];
  const float* bg1 = (const float*)d_in[5];
  const float* g1g = (const float*)d_in[6];
  const float* g1b = (const float*)d_in[7];
  const float* Wg2 = (const float*)d_in[8];
  const float* bg2 = (const float*)d_in[9];
  const float* g2g = (const float*)d_in[10];
  const float* g2b = (const float*)d_in[11];
  const float* Wgat = (const float*)d_in[12];
  const float* att_s = (const float*)d_in[13];
  const float* att_d = (const float*)d_in[14];
  const float* bgat = (const float*)d_in[15];
  const float* Wao = (const float*)d_in[16];
  const float* bao = (const float*)d_in[17];
  const float* Wout = (const float*)d_in[18];
  const float* bout = (const float*)d_in[19];

  const int N = in_sizes[0] / 256;
  const int E = in_sizes[1] / 2;
  const int* src = ei;
  const int* dst = ei + E;

  // ---- workspace layout (float elements), total ~210.4 MB ----
  float* F = (float*)d_ws;
  size_t o = 0;
  float* h0 = F + o;  o += (size_t)N * HID;
  float* xw = F + o;  o += (size_t)N * HID;
  float* x1 = F + o;  o += (size_t)N * HID;
  float* x2 = F + o;  o += (size_t)N * HID;
  float* gat = h0;                       // reuses h0|xw|x1|x2 (all dead by GAT agg)
  float* xwg = F + o; o += (size_t)N * GATD;
  float* att = xwg;                      // reuses xwg (dead after GAT agg)
  float* dinv = F + o; o += (size_t)N;
  float* a_s = F + o; o += (size_t)N * HEADS;
  float* a_d = F + o; o += (size_t)N * HEADS;
  int* I = (int*)(F + o);
  int* cnt = I;
  int* cur = I + N;
  int* rowp = I + 2 * N;
  int* colsrc = I + 3 * N + 1;

  const int eb = (E + TPB - 1) / TPB;
  const int nb = (N + TPB - 1) / TPB;
  const int zb = (2 * N + TPB - 1) / TPB;
  const int ab = (N + 3) / 4;
  const int gm = (N + 127) / 128;

  k_zero<<<zb, TPB, 0, stream>>>(cnt, 2 * N);  // cnt + cur
  k_hist<<<eb, TPB, 0, stream>>>(dst, cnt, E);
  k_dinv<<<nb, TPB, 0, stream>>>(cnt, dinv, N);
  k_scan<<<1, 1024, 0, stream>>>(cnt, rowp, N);
  k_fill<<<eb, TPB, 0, stream>>>(src, dst, rowp, cur, colsrc, E);

  // h0 = relu(x @ Win + bin)            [N,256]x[256,128]
  k_gemm_mfma<128, 4, true, true><<<dim3(gm, 1), 256, 0, stream>>>(x, Win, bin, h0, N, 256, 128);
  // GCN layer 1
  k_gemm_mfma<128, 4, false, false><<<dim3(gm, 1), 256, 0, stream>>>(h0, Wg1, nullptr, xw, N, 128, 128);
  k_gcn_agg<false><<<ab, 256, 0, stream>>>(xw, dinv, rowp, colsrc, bg1, g1g, g1b, nullptr, x1, N);
  // GCN layer 2 (+residual)
  k_gemm_mfma<128, 4, false, false><<<dim3(gm, 1), 256, 0, stream>>>(x1, Wg2, nullptr, xw, N, 128, 128);
  k_gcn_agg<true><<<ab, 256, 0, stream>>>(xw, dinv, rowp, colsrc, bg2, g2g, g2b, x1, x2, N);
  // GAT: xwg = x2 @ Wgat                [N,128]x[128,512]
  k_gemm_mfma<128, 4, false, false><<<dim3(gm, 4), 256, 0, stream>>>(x2, Wgat, nullptr, xwg, N, 128, 512);
  k_gat_scores<<<ab, 256, 0, stream>>>(xwg, att_s, att_d, a_s, a_d, N);
  k_gat_agg<<<ab, 256, 0, stream>>>(xwg, a_s, a_d, rowp, colsrc, bgat, gat, N);
  // att = relu(gat @ Wao + bao)         [N,512]x[512,128]
  k_gemm_mfma<128, 4, true, true><<<dim3(gm, 1), 256, 0, stream>>>(gat, Wao, bao, att, N, 512, 128);
  // out = att @ Wout + bout             [N,128]x[128,64]
  k_gemm_mfma<64, 2, false, true><<<dim3(gm, 1), 256, 0, stream>>>(att, Wout, bout, (float*)d_out, N, 128, 64);
}

// Round 4
// 700.971 us; speedup vs baseline: 1.3877x; 1.1431x over previous
//
#include <hip/hip_runtime.h>
#include <hip/hip_bf16.h>
#include <cstddef>
#include <cstdint>

#define TPB 256
#define HID 128
#define GATD 512
#define HEADS 4

typedef __attribute__((ext_vector_type(8))) short bf16x8;
typedef __attribute__((ext_vector_type(4))) float f32x4;

__device__ __forceinline__ float lrelu02(float x) { return x > 0.0f ? x : 0.2f * x; }

__device__ __forceinline__ unsigned short f2bf_rn(float f) {
  uint32_t u = __float_as_uint(f);
  u += 0x7fff + ((u >> 16) & 1);
  return (unsigned short)(u >> 16);
}
__device__ __forceinline__ float bf2f(unsigned short h) {
  return __uint_as_float(((uint32_t)h) << 16);
}
__device__ __forceinline__ float bflo(uint32_t u) { return __uint_as_float(u << 16); }
__device__ __forceinline__ float bfhi(uint32_t u) { return __uint_as_float(u & 0xffff0000u); }
__device__ __forceinline__ void split_bf(float a, unsigned short& hi, unsigned short& lo) {
  hi = f2bf_rn(a);
  lo = f2bf_rn(a - bf2f(hi));
}

// ---------------- utility ----------------
__global__ void k_zero(int* __restrict__ p, int n) {
  int i = blockIdx.x * blockDim.x + threadIdx.x;
  if (i < n) p[i] = 0;
}

// ---------------- CSR build ----------------
__global__ void k_hist(const int* __restrict__ dst, int* __restrict__ cnt, int E) {
  int i = blockIdx.x * blockDim.x + threadIdx.x;
  if (i < E) atomicAdd(&cnt[dst[i]], 1);
}

__global__ void k_dinv(const int* __restrict__ cnt, float* __restrict__ dinv, int n) {
  int i = blockIdx.x * blockDim.x + threadIdx.x;
  if (i < n) dinv[i] = rsqrtf((float)(cnt[i] + 1));  // +1 = self loop
}

__global__ __launch_bounds__(1024) void k_scan(const int* __restrict__ cnt,
                                               int* __restrict__ rowp, int n) {
  __shared__ int sm[1024];
  __shared__ int carry;
  const int tid = threadIdx.x;
  if (tid == 0) carry = 0;
  __syncthreads();
  for (int base = 0; base < n; base += 1024) {
    int idx = base + tid;
    int v = (idx < n) ? cnt[idx] : 0;
    sm[tid] = v;
    __syncthreads();
    for (int off = 1; off < 1024; off <<= 1) {
      int t = (tid >= off) ? sm[tid - off] : 0;
      __syncthreads();
      sm[tid] += t;
      __syncthreads();
    }
    int incl = sm[tid];
    int c = carry;
    if (idx < n) rowp[idx] = c + incl - v;  // exclusive
    __syncthreads();
    if (tid == 1023) carry = c + sm[1023];
    __syncthreads();
  }
  if (tid == 0) rowp[n] = carry;
}

__global__ void k_fill(const int* __restrict__ src, const int* __restrict__ dst,
                       const int* __restrict__ rowp, int* __restrict__ cur,
                       int* __restrict__ colsrc, int E) {
  int i = blockIdx.x * blockDim.x + threadIdx.x;
  if (i < E) {
    int d = dst[i];
    int pos = rowp[d] + atomicAdd(&cur[d], 1);
    colsrc[pos] = src[i];
  }
}

// ---------------- MFMA GEMM with split-bf16 (hi/lo) emulated fp32 ----------------
// C = act(A[M,K] @ W[K,NC] + bias).  BM=128, BK=32, 4 waves 2x2.
// A*B ~= Ah*Bh + Ah*Bl + Al*Bh  (error ~2^-17 rel).
// OBF16: write output as bf16 (round-to-nearest) instead of fp32.
template <int BN, int WCF, bool RELU, bool BIAS, bool OBF16>
__global__ __launch_bounds__(256) void k_gemm_mfma(const float* __restrict__ A,
                                                   const float* __restrict__ W,
                                                   const float* __restrict__ bias,
                                                   void* __restrict__ Cv,
                                                   int M, int K, int NC) {
  constexpr int BM = 128;
  constexpr int LOG2BN = (BN == 128) ? 7 : 6;
  __shared__ alignas(16) unsigned short Ah[4][BM][8], Al[4][BM][8];
  __shared__ alignas(16) unsigned short Bh[4][BN][8], Bl[4][BN][8];

  const int tid = threadIdx.x;
  const int lane = tid & 63;
  const int wid = tid >> 6;
  const int wr = wid >> 1, wc = wid & 1;
  const int m0 = blockIdx.x * BM;
  const int n0 = blockIdx.y * BN;

  f32x4 acc[4][WCF];
#pragma unroll
  for (int mr = 0; mr < 4; ++mr)
#pragma unroll
    for (int nc = 0; nc < WCF; ++nc) acc[mr][nc] = (f32x4){0.f, 0.f, 0.f, 0.f};

  const int arow = tid >> 1;      // 0..127
  const int ahalf = tid & 1;      // which 16-k half
  const bool aok = (m0 + arow) < M;
  const float* Ap = A + (size_t)(m0 + arow) * K + ahalf * 16;
  const int fr = lane & 15;       // frag row/col
  const int g = lane >> 4;        // k-group

  for (int k0 = 0; k0 < K; k0 += 32) {
    // ---- stage A (fp32 -> hi/lo bf16) ----
    float av[16];
    if (aok) {
      const float4* p = (const float4*)(Ap + k0);
      float4 q0 = p[0], q1 = p[1], q2 = p[2], q3 = p[3];
      av[0] = q0.x; av[1] = q0.y; av[2] = q0.z; av[3] = q0.w;
      av[4] = q1.x; av[5] = q1.y; av[6] = q1.z; av[7] = q1.w;
      av[8] = q2.x; av[9] = q2.y; av[10] = q2.z; av[11] = q2.w;
      av[12] = q3.x; av[13] = q3.y; av[14] = q3.z; av[15] = q3.w;
    } else {
#pragma unroll
      for (int j = 0; j < 16; ++j) av[j] = 0.f;
    }
#pragma unroll
    for (int gg = 0; gg < 2; ++gg) {
      uint32_t hw[4], lw[4];
#pragma unroll
      for (int q = 0; q < 4; ++q) {
        unsigned short h0, l0, h1, l1;
        split_bf(av[gg * 8 + 2 * q], h0, l0);
        split_bf(av[gg * 8 + 2 * q + 1], h1, l1);
        hw[q] = (uint32_t)h0 | ((uint32_t)h1 << 16);
        lw[q] = (uint32_t)l0 | ((uint32_t)l1 << 16);
      }
      const int kg = ahalf * 2 + gg;
      *(uint4*)&Ah[kg][arow][0] = make_uint4(hw[0], hw[1], hw[2], hw[3]);
      *(uint4*)&Al[kg][arow][0] = make_uint4(lw[0], lw[1], lw[2], lw[3]);
    }
    // ---- stage B ----
#pragma unroll
    for (int b = 0; b < (BN * 4) / 256; ++b) {
      const int it = tid + b * 256;
      const int n = it & (BN - 1);
      const int kg = it >> LOG2BN;
      const float* Wp = W + (size_t)(k0 + kg * 8) * NC + n0 + n;
      uint32_t hw[4], lw[4];
#pragma unroll
      for (int q = 0; q < 4; ++q) {
        float v0 = Wp[(size_t)(2 * q) * NC];
        float v1 = Wp[(size_t)(2 * q + 1) * NC];
        unsigned short h0, l0, h1, l1;
        split_bf(v0, h0, l0);
        split_bf(v1, h1, l1);
        hw[q] = (uint32_t)h0 | ((uint32_t)h1 << 16);
        lw[q] = (uint32_t)l0 | ((uint32_t)l1 << 16);
      }
      *(uint4*)&Bh[kg][n][0] = make_uint4(hw[0], hw[1], hw[2], hw[3]);
      *(uint4*)&Bl[kg][n][0] = make_uint4(lw[0], lw[1], lw[2], lw[3]);
    }
    __syncthreads();
    // ---- frags + MFMA ----
    bf16x8 ahf[4], alf[4], bhf[WCF], blf[WCF];
#pragma unroll
    for (int mr = 0; mr < 4; ++mr) {
      const int row = wr * 64 + mr * 16 + fr;
      ahf[mr] = *(const bf16x8*)&Ah[g][row][0];
      alf[mr] = *(const bf16x8*)&Al[g][row][0];
    }
#pragma unroll
    for (int nc = 0; nc < WCF; ++nc) {
      const int col = wc * WCF * 16 + nc * 16 + fr;
      bhf[nc] = *(const bf16x8*)&Bh[g][col][0];
      blf[nc] = *(const bf16x8*)&Bl[g][col][0];
    }
#pragma unroll
    for (int mr = 0; mr < 4; ++mr)
#pragma unroll
      for (int nc = 0; nc < WCF; ++nc) {
        acc[mr][nc] = __builtin_amdgcn_mfma_f32_16x16x32_bf16(ahf[mr], bhf[nc], acc[mr][nc], 0, 0, 0);
        acc[mr][nc] = __builtin_amdgcn_mfma_f32_16x16x32_bf16(ahf[mr], blf[nc], acc[mr][nc], 0, 0, 0);
        acc[mr][nc] = __builtin_amdgcn_mfma_f32_16x16x32_bf16(alf[mr], bhf[nc], acc[mr][nc], 0, 0, 0);
      }
    __syncthreads();
  }
  // ---- epilogue ----
#pragma unroll
  for (int mr = 0; mr < 4; ++mr) {
#pragma unroll
    for (int nc = 0; nc < WCF; ++nc) {
      const int col = n0 + wc * WCF * 16 + nc * 16 + fr;
      const float bv = BIAS ? bias[col] : 0.f;
#pragma unroll
      for (int r = 0; r < 4; ++r) {
        const int grow = m0 + wr * 64 + mr * 16 + g * 4 + r;
        if (grow < M) {
          float v = acc[mr][nc][r] + bv;
          if (RELU) v = fmaxf(v, 0.f);
          if (OBF16)
            ((unsigned short*)Cv)[(size_t)grow * NC + col] = f2bf_rn(v);
          else
            ((float*)Cv)[(size_t)grow * NC + col] = v;
        }
      }
    }
  }
}

// ---------------- GCN aggregate + bias + LayerNorm + ReLU (+residual), wave/node ----------------
template <bool RES>
__global__ __launch_bounds__(256) void k_gcn_agg(const float* __restrict__ xw,
                                                 const float* __restrict__ dinv,
                                                 const int* __restrict__ rowp,
                                                 const int* __restrict__ colsrc,
                                                 const float* __restrict__ bias,
                                                 const float* __restrict__ gamma,
                                                 const float* __restrict__ beta,
                                                 const float* __restrict__ resid,
                                                 float* __restrict__ out, int n) {
  const int lane = threadIdx.x & 63;
  const int i = blockIdx.x * 4 + (threadIdx.x >> 6);
  if (i >= n) return;
  const float di = dinv[i];
  const int c = lane * 2;
  float2 v = *(const float2*)(xw + (size_t)i * HID + c);
  float a0 = v.x * di * di, a1 = v.y * di * di;  // self loop
  const int e0 = rowp[i], e1 = rowp[i + 1];
  for (int j = e0; j < e1; ++j) {
    int s = colsrc[j];
    float w = dinv[s] * di;
    float2 u = *(const float2*)(xw + (size_t)s * HID + c);
    a0 = fmaf(u.x, w, a0);
    a1 = fmaf(u.y, w, a1);
  }
  a0 += bias[c];
  a1 += bias[c + 1];
  float s1 = a0 + a1, s2 = a0 * a0 + a1 * a1;
#pragma unroll
  for (int m = 32; m >= 1; m >>= 1) {
    s1 += __shfl_xor(s1, m);
    s2 += __shfl_xor(s2, m);
  }
  float mu = s1 * (1.0f / HID);
  float var = s2 * (1.0f / HID) - mu * mu;
  float rstd = rsqrtf(var + 1e-5f);
  float y0 = fmaxf((a0 - mu) * rstd * gamma[c] + beta[c], 0.0f);
  float y1 = fmaxf((a1 - mu) * rstd * gamma[c + 1] + beta[c + 1], 0.0f);
  if (RES) {
    float2 r = *(const float2*)(resid + (size_t)i * HID + c);
    y0 += r.x;
    y1 += r.y;
  }
  *(float2*)(out + (size_t)i * HID + c) = make_float2(y0, y1);
}

// ---------------- fold Wgat into attention vectors: waT[p][k], p<4: src head p; p>=4: dst head p-4 ----------------
__global__ __launch_bounds__(256) void k_wprep(const float* __restrict__ Wgat,
                                               const float* __restrict__ att_src,
                                               const float* __restrict__ att_dst,
                                               float* __restrict__ waT) {
  int t = blockIdx.x * blockDim.x + threadIdx.x;  // 0..1023
  if (t >= 1024) return;
  int p = t >> 7, k = t & 127;
  int h = p & 3;
  const float* av = (p < 4 ? att_src : att_dst) + h * HID;
  const float* wrow = Wgat + (size_t)k * GATD + h * HID;
  float s = 0.f;
#pragma unroll 4
  for (int c = 0; c < HID; ++c) s = fmaf(wrow[c], av[c], s);
  waT[t] = s;
}

// ---------------- a_s/a_d = x2 @ waT^T (fp32 exact logits), wave/node ----------------
__global__ __launch_bounds__(256) void k_asd(const float* __restrict__ x2,
                                             const float* __restrict__ waT,
                                             float* __restrict__ a_s,
                                             float* __restrict__ a_d, int n) {
  __shared__ float w[8][HID];
  for (int t = threadIdx.x; t < 8 * HID; t += 256) ((float*)w)[t] = waT[t];
  __syncthreads();
  const int lane = threadIdx.x & 63;
  const int i = blockIdx.x * 4 + (threadIdx.x >> 6);
  if (i >= n) return;
  const int c = lane * 2;
  float2 xv = *(const float2*)(x2 + (size_t)i * HID + c);
  float p0 = xv.x * w[0][c] + xv.y * w[0][c + 1];
  float p1 = xv.x * w[1][c] + xv.y * w[1][c + 1];
  float p2 = xv.x * w[2][c] + xv.y * w[2][c + 1];
  float p3 = xv.x * w[3][c] + xv.y * w[3][c + 1];
  float p4 = xv.x * w[4][c] + xv.y * w[4][c + 1];
  float p5 = xv.x * w[5][c] + xv.y * w[5][c + 1];
  float p6 = xv.x * w[6][c] + xv.y * w[6][c + 1];
  float p7 = xv.x * w[7][c] + xv.y * w[7][c + 1];
#pragma unroll
  for (int m = 32; m >= 1; m >>= 1) {
    p0 += __shfl_xor(p0, m); p1 += __shfl_xor(p1, m);
    p2 += __shfl_xor(p2, m); p3 += __shfl_xor(p3, m);
    p4 += __shfl_xor(p4, m); p5 += __shfl_xor(p5, m);
    p6 += __shfl_xor(p6, m); p7 += __shfl_xor(p7, m);
  }
  if (lane == 0) {
    a_s[i * 4 + 0] = p0; a_s[i * 4 + 1] = p1; a_s[i * 4 + 2] = p2; a_s[i * 4 + 3] = p3;
    a_d[i * 4 + 0] = p4; a_d[i * 4 + 1] = p5; a_d[i * 4 + 2] = p6; a_d[i * 4 + 3] = p7;
  }
}

// ---------------- GAT softmax-aggregate (wave/node), bf16 message table ----------------
__global__ __launch_bounds__(256) void k_gat_agg(const unsigned short* __restrict__ xwgb,
                                                 const float* __restrict__ a_s,
                                                 const float* __restrict__ a_d,
                                                 const int* __restrict__ rowp,
                                                 const int* __restrict__ colsrc,
                                                 const float* __restrict__ bias,
                                                 float* __restrict__ out, int n) {
  const int lane = threadIdx.x & 63;
  const int i = blockIdx.x * 4 + (threadIdx.x >> 6);
  if (i >= n) return;
  const float4 adv = *(const float4*)(a_d + i * 4);
  const float4 asv = *(const float4*)(a_s + i * 4);
  float es0 = lrelu02(asv.x + adv.x);
  float es1 = lrelu02(asv.y + adv.y);
  float es2 = lrelu02(asv.z + adv.z);
  float es3 = lrelu02(asv.w + adv.w);
  const int e0 = rowp[i], e1 = rowp[i + 1];
  float m0 = es0, m1 = es1, m2 = es2, m3 = es3;
  for (int j = e0 + lane; j < e1; j += 64) {
    int s = colsrc[j];
    const float4 av = *(const float4*)(a_s + s * 4);
    m0 = fmaxf(m0, lrelu02(av.x + adv.x));
    m1 = fmaxf(m1, lrelu02(av.y + adv.y));
    m2 = fmaxf(m2, lrelu02(av.z + adv.z));
    m3 = fmaxf(m3, lrelu02(av.w + adv.w));
  }
#pragma unroll
  for (int m = 32; m >= 1; m >>= 1) {
    m0 = fmaxf(m0, __shfl_xor(m0, m));
    m1 = fmaxf(m1, __shfl_xor(m1, m));
    m2 = fmaxf(m2, __shfl_xor(m2, m));
    m3 = fmaxf(m3, __shfl_xor(m3, m));
  }
  float d0 = 0.f, d1 = 0.f, d2 = 0.f, d3 = 0.f;
  for (int j = e0 + lane; j < e1; j += 64) {
    int s = colsrc[j];
    const float4 av = *(const float4*)(a_s + s * 4);
    d0 += __expf(lrelu02(av.x + adv.x) - m0);
    d1 += __expf(lrelu02(av.y + adv.y) - m1);
    d2 += __expf(lrelu02(av.z + adv.z) - m2);
    d3 += __expf(lrelu02(av.w + adv.w) - m3);
  }
#pragma unroll
  for (int m = 32; m >= 1; m >>= 1) {
    d0 += __shfl_xor(d0, m);
    d1 += __shfl_xor(d1, m);
    d2 += __shfl_xor(d2, m);
    d3 += __shfl_xor(d3, m);
  }
  d0 += __expf(es0 - m0);
  d1 += __expf(es1 - m1);
  d2 += __expf(es2 - m2);
  d3 += __expf(es3 - m3);
  const float inv0 = 1.0f / d0, inv1 = 1.0f / d1, inv2 = 1.0f / d2, inv3 = 1.0f / d3;
  const int col = lane * 8;
  const int h = lane >> 4;
  const float mh = (h < 2) ? (h == 0 ? m0 : m1) : (h == 2 ? m2 : m3);
  const float invh = (h < 2) ? (h == 0 ? inv0 : inv1) : (h == 2 ? inv2 : inv3);
  const float adh = (h < 2) ? (h == 0 ? adv.x : adv.y) : (h == 2 ? adv.z : adv.w);
  const float esh = (h < 2) ? (h == 0 ? es0 : es1) : (h == 2 ? es2 : es3);
  // pass 3: alpha-weighted bf16 message accumulation (init = self loop)
  const float aself = __expf(esh - mh) * invh;
  uint4 u = *(const uint4*)(xwgb + (size_t)i * GATD + col);
  float4 acc0 = make_float4(bflo(u.x) * aself, bfhi(u.x) * aself,
                            bflo(u.y) * aself, bfhi(u.y) * aself);
  float4 acc1 = make_float4(bflo(u.z) * aself, bfhi(u.z) * aself,
                            bflo(u.w) * aself, bfhi(u.w) * aself);
  for (int j = e0; j < e1; ++j) {
    int s = colsrc[j];
    float al = __expf(lrelu02(a_s[s * 4 + h] + adh) - mh) * invh;
    uint4 w = *(const uint4*)(xwgb + (size_t)s * GATD + col);
    acc0.x = fmaf(bflo(w.x), al, acc0.x); acc0.y = fmaf(bfhi(w.x), al, acc0.y);
    acc0.z = fmaf(bflo(w.y), al, acc0.z); acc0.w = fmaf(bfhi(w.y), al, acc0.w);
    acc1.x = fmaf(bflo(w.z), al, acc1.x); acc1.y = fmaf(bfhi(w.z), al, acc1.y);
    acc1.z = fmaf(bflo(w.w), al, acc1.z); acc1.w = fmaf(bfhi(w.w), al, acc1.w);
  }
  const float4* bp = (const float4*)(bias + col);
  float4 b0 = bp[0], b1 = bp[1];
  acc0.x += b0.x; acc0.y += b0.y; acc0.z += b0.z; acc0.w += b0.w;
  acc1.x += b1.x; acc1.y += b1.y; acc1.z += b1.z; acc1.w += b1.w;
  float4* op = (float4*)(out + (size_t)i * GATD + col);
  op[0] = acc0;
  op[1] = acc1;
}

extern "C" void kernel_launch(void* const* d_in, const int* in_sizes, int n_in,
                              void* d_out, int out_size, void* d_ws, size_t ws_size,
                              hipStream_t stream) {
  const float* x = (const float*)d_in[0];
  const int* ei = (const int*)d_in[1];
  const float* Win = (const float*)d_in[2];
  const float* bin = (const float*)d_in[3];
  const float* Wg1 = (const float*)d_in[4];
  const float* bg1 = (const float*)d_in[5];
  const float* g1g = (const float*)d_in[6];
  const float* g1b = (const float*)d_in[7];
  const float* Wg2 = (const float*)d_in[8];
  const float* bg2 = (const float*)d_in[9];
  const float* g2g = (const float*)d_in[10];
  const float* g2b = (const float*)d_in[11];
  const float* Wgat = (const float*)d_in[12];
  const float* att_s = (const float*)d_in[13];
  const float* att_d = (const float*)d_in[14];
  const float* bgat = (const float*)d_in[15];
  const float* Wao = (const float*)d_in[16];
  const float* bao = (const float*)d_in[17];
  const float* Wout = (const float*)d_in[18];
  const float* bout = (const float*)d_in[19];

  const int N = in_sizes[0] / 256;
  const int E = in_sizes[1] / 2;
  const int* src = ei;
  const int* dst = ei + E;

  // ---- workspace layout (float elements) ----
  // reuse region: h0|xw|x1|x2 = N*512 floats, later reused as gat[N,512] fp32
  // xwgb: N*512 bf16 (= N*256 floats), later reused as att[N,128] fp32
  float* F = (float*)d_ws;
  size_t o = 0;
  float* h0 = F + o;  o += (size_t)N * HID;
  float* xw = F + o;  o += (size_t)N * HID;
  float* x1 = F + o;  o += (size_t)N * HID;
  float* x2 = F + o;  o += (size_t)N * HID;
  float* gat = h0;                         // aliases h0..x2 (dead by GAT agg)
  unsigned short* xwgb = (unsigned short*)(F + o); o += (size_t)N * GATD / 2;
  float* att = (float*)xwgb;               // aliases xwgb (dead after GAT agg)
  float* dinv = F + o; o += (size_t)N;
  float* a_s = F + o; o += (size_t)N * HEADS;
  float* a_d = F + o; o += (size_t)N * HEADS;
  float* waT = F + o; o += 1024;
  int* I = (int*)(F + o);
  int* cnt = I;
  int* cur = I + N;
  int* rowp = I + 2 * N;
  int* colsrc = I + 3 * N + 1;

  const int eb = (E + TPB - 1) / TPB;
  const int nb = (N + TPB - 1) / TPB;
  const int zb = (2 * N + TPB - 1) / TPB;
  const int ab = (N + 3) / 4;
  const int gm = (N + 127) / 128;

  k_zero<<<zb, TPB, 0, stream>>>(cnt, 2 * N);  // cnt + cur
  k_hist<<<eb, TPB, 0, stream>>>(dst, cnt, E);
  k_dinv<<<nb, TPB, 0, stream>>>(cnt, dinv, N);
  k_scan<<<1, 1024, 0, stream>>>(cnt, rowp, N);
  k_fill<<<eb, TPB, 0, stream>>>(src, dst, rowp, cur, colsrc, E);
  k_wprep<<<4, 256, 0, stream>>>(Wgat, att_s, att_d, waT);

  // h0 = relu(x @ Win + bin)            [N,256]x[256,128]
  k_gemm_mfma<128, 4, true, true, false><<<dim3(gm, 1), 256, 0, stream>>>(x, Win, bin, h0, N, 256, 128);
  // GCN layer 1
  k_gemm_mfma<128, 4, false, false, false><<<dim3(gm, 1), 256, 0, stream>>>(h0, Wg1, nullptr, xw, N, 128, 128);
  k_gcn_agg<false><<<ab, 256, 0, stream>>>(xw, dinv, rowp, colsrc, bg1, g1g, g1b, nullptr, x1, N);
  // GCN layer 2 (+residual)
  k_gemm_mfma<128, 4, false, false, false><<<dim3(gm, 1), 256, 0, stream>>>(x1, Wg2, nullptr, xw, N, 128, 128);
  k_gcn_agg<true><<<ab, 256, 0, stream>>>(xw, dinv, rowp, colsrc, bg2, g2g, g2b, x1, x2, N);
  // GAT: xwgb = bf16(x2 @ Wgat)         [N,128]x[128,512]
  k_gemm_mfma<128, 4, false, false, true><<<dim3(gm, 4), 256, 0, stream>>>(x2, Wgat, nullptr, xwgb, N, 128, 512);
  // exact fp32 attention logits from x2 (not from bf16 xwgb)
  k_asd<<<ab, 256, 0, stream>>>(x2, waT, a_s, a_d, N);
  k_gat_agg<<<ab, 256, 0, stream>>>(xwgb, a_s, a_d, rowp, colsrc, bgat, gat, N);
  // att = relu(gat @ Wao + bao)         [N,512]x[512,128]
  k_gemm_mfma<128, 4, true, true, false><<<dim3(gm, 1), 256, 0, stream>>>(gat, Wao, bao, att, N, 512, 128);
  // out = att @ Wout + bout             [N,128]x[128,64]
  k_gemm_mfma<64, 2, false, true, false><<<dim3(gm, 1), 256, 0, stream>>>(att, Wout, bout, d_out, N, 128, 64);
}